// Round 6
// baseline (160.298 us; speedup 1.0000x reference)
//
#include <hip/hip_runtime.h>

#define LRELU_ALPHA 0.2f

constexpr int NN    = 4096;
constexpr int FIN   = 512;
constexpr int NH    = 8;
constexpr int FOUT  = 64;
constexpr int NFLAT = NH * FOUT; // 512
constexpr float LOG2E = 1.4426950408889634f;

typedef __attribute__((ext_vector_type(8))) __bf16 bf16x8;
typedef __attribute__((ext_vector_type(4))) __bf16 bf16x4;
typedef __attribute__((ext_vector_type(4))) float f32x4;
typedef __attribute__((ext_vector_type(2))) float f32x2;

// ================= k_prep: wtsw + Wa (small, no adj) =================
// blocks [0,64): W -> wtsw (bf16, pre-swizzled for k_main gemm's global_load_lds)
// blocks [64,96): Wa[k][o] = log2e * sum_f W[k][(o&7)*64+f] * a[(o>>3)*64+f]
__global__ __launch_bounds__(256) void k_prep(const float* __restrict__ W,
                                              const float* __restrict__ a,
                                              __bf16* __restrict__ wtsw,
                                              float* __restrict__ Wa) {
    __shared__ float tile[64][68];
    const int bid = blockIdx.x;
    const int t = threadIdx.x;
    if (bid < 64) {
        const int kt = bid >> 3;
        const int fb = (bid & 7) * 64;
        {
            const int kk = t >> 2, cq = (t & 3) * 16;
            #pragma unroll
            for (int i = 0; i < 4; ++i)
                *(float4*)&tile[kk][cq + i * 4] =
                    *(const float4*)&W[(size_t)(kt * 64 + kk) * NFLAT + fb + cq + i * 4];
        }
        __syncthreads();
        const int fl = t >> 2;
        #pragma unroll
        for (int c = 0; c < 2; ++c) {
            int gs = (t & 3) * 2 + c;
            int g  = gs ^ (fl & 7);
            bf16x8 o;
            #pragma unroll
            for (int jo = 0; jo < 8; ++jo) o[jo] = (__bf16)tile[g * 8 + jo][fl];
            *(bf16x8*)&wtsw[((size_t)(kt * NFLAT + fb + fl)) * 64 + gs * 8] = o;
        }
    } else {
        const int k = (bid - 64) * 16 + (t >> 4);
        const int o = t & 15;
        const float* wrow = &W[(size_t)k * NFLAT + (o & 7) * 64];
        const float* av   = &a[(o >> 3) * 64];
        float acc = 0.f;
        #pragma unroll 8
        for (int f = 0; f < 64; ++f) acc = fmaf(wrow[f], av[f], acc);
        Wa[k * 16 + o] = acc * LOG2E;
    }
}

// ================= k_main: gemm(->whtB) + f12(->f1T,f2p,f2n) + bitmask, one dispatch =====
__global__ __launch_bounds__(256) void k_main(const float* __restrict__ x,
                                              const int* __restrict__ adj,
                                              const __bf16* __restrict__ wtsw,
                                              const float* __restrict__ Wa,
                                              __bf16* __restrict__ whtB,
                                              float* __restrict__ f1T,
                                              float* __restrict__ f2p,
                                              float* __restrict__ f2n,
                                              unsigned long long* __restrict__ bmT,
                                              float* __restrict__ oacc,
                                              float* __restrict__ lsumg) {
    __shared__ alignas(16) __bf16 Bs[2][64 * 64];
    const int bid = blockIdx.x;
    const int t = threadIdx.x;
    if (bid < 512) {
        // ---- Wh = bf16(x) @ bf16(W), epilogue -> fragment-ordered whtB ----
        const int wv = t >> 6, l = t & 63;
        const int jt = bid & 63, h = bid >> 6;
        const int bm = jt * 64, bn = h * 64;
        const int lm = l & 15, lk = l >> 4;
        const int swB = (lm & 7) << 4;

        // free-rider zero-init
        {
            float4 z = make_float4(0.f, 0.f, 0.f, 0.f);
            float4* od = (float4*)oacc;
            #pragma unroll
            for (int i = 0; i < 4; ++i) od[(size_t)bid * 1024 + t * 4 + i] = z;
            if (bid < 32) ((float4*)lsumg)[bid * 256 + t] = z;
        }

        f32x4 acc[4] = {};
        auto stageB = [&](int kt, int bb) {
            #pragma unroll
            for (int kq = 0; kq < 2; ++kq) {
                int u = t + kq * 256;
                __builtin_amdgcn_global_load_lds(
                    (const __attribute__((address_space(1))) void*)(wtsw + (size_t)(kt * NFLAT + bn) * 64 + u * 8),
                    (__attribute__((address_space(3))) void*)((char*)&Bs[bb][0] + u * 16), 16, 0, 0);
            }
        };

        stageB(0, 0);
        const float* xrow = &x[(size_t)(bm + wv * 16 + lm) * FIN + lk * 8];
        for (int kt = 0; kt < 8; ++kt) {
            bf16x8 aF[2];
            #pragma unroll
            for (int ks = 0; ks < 2; ++ks) {
                float4 u0 = *(const float4*)&xrow[kt * 64 + ks * 32];
                float4 u1 = *(const float4*)&xrow[kt * 64 + ks * 32 + 4];
                bf16x8 af;
                af[0] = (__bf16)u0.x; af[1] = (__bf16)u0.y; af[2] = (__bf16)u0.z; af[3] = (__bf16)u0.w;
                af[4] = (__bf16)u1.x; af[5] = (__bf16)u1.y; af[6] = (__bf16)u1.z; af[7] = (__bf16)u1.w;
                aF[ks] = af;
            }
            __syncthreads();
            if (kt < 7) stageB(kt + 1, (kt + 1) & 1);
            const char* wb = (const char*)&Bs[kt & 1][0];
            #pragma unroll
            for (int q = 0; q < 4; ++q) {
                #pragma unroll
                for (int ks = 0; ks < 2; ++ks) {
                    bf16x8 bF = *(const bf16x8*)(wb + (((q * 16 + lm) * 128 + lk * 16 + ks * 64) ^ swB));
                    acc[q] = __builtin_amdgcn_mfma_f32_16x16x32_bf16(aF[ks], bF, acc[q], 0, 0, 0);
                }
            }
        }
        __syncthreads();                       // Bs dead
        __bf16* T = (__bf16*)&Bs[0][0];        // [64 f][stride 72]
        constexpr int TS = 72;
        #pragma unroll
        for (int q = 0; q < 4; ++q) {
            bf16x4 v;
            #pragma unroll
            for (int r = 0; r < 4; ++r) v[r] = (__bf16)acc[q][r];
            *(bf16x4*)&T[(q * 16 + lm) * TS + wv * 16 + lk * 4] = v;
        }
        __syncthreads();
        #pragma unroll
        for (int half = 0; half < 2; ++half) {
            const int fid = (t >> 6) + half * 4;   // 0..7 = q*2+ks
            const int q = fid >> 1, ks = fid & 1;
            const int f = q * 16 + lm, j0 = ks * 32 + lk * 8;
            bf16x8 frag = *(const bf16x8*)&T[f * TS + j0];
            *(bf16x8*)&whtB[(((size_t)jt * NH + h) * 8 + fid) * 512 + l * 8] = frag;
        }
    } else if (bid < 768) {
        // ---- f12: f1 raw; f2 pre-exponentiated (pos/neg branches) ----
        const int n = (bid - 512) * 16 + (t >> 4);
        const int o = t & 15;
        const float* xrow = &x[(size_t)n * FIN];
        float acc = 0.f;
        for (int k0 = 0; k0 < FIN; k0 += 4) {
            float4 xv = *(const float4*)&xrow[k0];
            acc = fmaf(xv.x, Wa[(k0 + 0) * 16 + o], acc);
            acc = fmaf(xv.y, Wa[(k0 + 1) * 16 + o], acc);
            acc = fmaf(xv.z, Wa[(k0 + 2) * 16 + o], acc);
            acc = fmaf(xv.w, Wa[(k0 + 3) * 16 + o], acc);
        }
        if (o >> 3) {
            f2p[(o & 7) * NN + n] = exp2f(acc);
            f2n[(o & 7) * NN + n] = exp2f(LRELU_ALPHA * acc);
        } else {
            f1T[(o & 7) * NN + n] = acc;
        }
    } else {
        // ---- bitmask pack: adj -> bmT[jt*NN + i], grid-stride ----
        const size_t base = (size_t)(bid - 768) * 16384;
        for (int it = 0; it < 64; ++it) {
            size_t idx = base + (size_t)it * 256 + t;
            int v = adj[idx];
            unsigned long long b = __ballot(v > 0);
            if ((t & 63) == 0) {
                int i = (int)(idx >> 12);
                int jt = (int)((idx >> 6) & 63);
                bmT[(size_t)jt * NN + i] = b;
            }
        }
    }
}

// ================= k_attn: register-pipelined, zero LDS/barriers =================
// p = max(E1p*F2p, E1n*F2n)  [exp2∘lrelu via monotonicity], mask via bfe sign-extend.
struct Tile {
    bf16x8 bF[4][2];
    float4 p0[2], p1[2], n0[2], n1[2];
    unsigned mk[2];
};

__global__ __launch_bounds__(256, 3) void k_attn(const unsigned long long* __restrict__ bmT,
                                                 const __bf16* __restrict__ whtB,
                                                 const float* __restrict__ f1T,
                                                 const float* __restrict__ f2p,
                                                 const float* __restrict__ f2n,
                                                 float* __restrict__ oacc,
                                                 float* __restrict__ lsumg) {
    const int t   = threadIdx.x;
    const int wv  = t >> 6, l = t & 63;
    const int gi0 = blockIdx.x * 64;
    const int h   = blockIdx.y;
    constexpr int NT = 16;                      // 64 tiles / jsplit 4
    const int jt0 = blockIdx.z * NT;

    const int lm = l & 15, lk = l >> 4;
    const int iA = wv * 16 + lm;
    const float f1v = f1T[h * NN + gi0 + iA];
    const float E1p = exp2f(f1v);
    const float E1n = exp2f(LRELU_ALPHA * f1v);
    const f32x2 e1p2 = {E1p, E1p}, e1n2 = {E1n, E1n};

    f32x4 acc[4] = {};
    f32x4 accl = {};
    bf16x8 ones;
    #pragma unroll
    for (int e = 0; e < 8; ++e) ones[e] = (__bf16)1.0f;

    auto load_tile = [&](Tile& T, int jt) {
        const __bf16* bb = whtB + (((size_t)jt * NH + h) * 8) * 512 + l * 8;
        #pragma unroll
        for (int q = 0; q < 4; ++q)
            #pragma unroll
            for (int ks = 0; ks < 2; ++ks)
                T.bF[q][ks] = *(const bf16x8*)(bb + (q * 2 + ks) * 512);
        #pragma unroll
        for (int ks = 0; ks < 2; ++ks) {
            const float* pp = f2p + h * NN + jt * 64 + ks * 32 + lk * 8;
            const float* pn = f2n + h * NN + jt * 64 + ks * 32 + lk * 8;
            T.p0[ks] = *(const float4*)pp;  T.p1[ks] = *(const float4*)(pp + 4);
            T.n0[ks] = *(const float4*)pn;  T.n1[ks] = *(const float4*)(pn + 4);
        }
        unsigned long long m = bmT[(size_t)jt * NN + gi0 + iA];
        T.mk[0] = (unsigned)(m >> (lk * 8));
        T.mk[1] = (unsigned)(m >> (32 + lk * 8));
    };

    auto process = [&](const Tile& T) {
        bf16x8 aF[2];
        #pragma unroll
        for (int ks = 0; ks < 2; ++ks) {
            const float fp[8] = {T.p0[ks].x, T.p0[ks].y, T.p0[ks].z, T.p0[ks].w,
                                 T.p1[ks].x, T.p1[ks].y, T.p1[ks].z, T.p1[ks].w};
            const float fn[8] = {T.n0[ks].x, T.n0[ks].y, T.n0[ks].z, T.n0[ks].w,
                                 T.n1[ks].x, T.n1[ks].y, T.n1[ks].z, T.n1[ks].w};
            const unsigned mk = T.mk[ks];
            bf16x8 pk;
            #pragma unroll
            for (int u = 0; u < 4; ++u) {
                f32x2 va = e1p2 * f32x2{fp[2 * u], fp[2 * u + 1]};
                f32x2 vb = e1n2 * f32x2{fn[2 * u], fn[2 * u + 1]};
                f32x2 pm = __builtin_elementwise_max(va, vb);
                unsigned m0 = (unsigned)(((int)(mk << (31 - (2 * u)))) >> 31);
                unsigned m1 = (unsigned)(((int)(mk << (31 - (2 * u + 1)))) >> 31);
                pk[2 * u]     = (__bf16)__uint_as_float(__float_as_uint(pm.x) & m0);
                pk[2 * u + 1] = (__bf16)__uint_as_float(__float_as_uint(pm.y) & m1);
            }
            aF[ks] = pk;
        }
        #pragma unroll
        for (int q = 0; q < 4; ++q) {
            acc[q] = __builtin_amdgcn_mfma_f32_16x16x32_bf16(aF[0], T.bF[q][0], acc[q], 0, 0, 0);
            acc[q] = __builtin_amdgcn_mfma_f32_16x16x32_bf16(aF[1], T.bF[q][1], acc[q], 0, 0, 0);
        }
        accl = __builtin_amdgcn_mfma_f32_16x16x32_bf16(aF[0], ones, accl, 0, 0, 0);
        accl = __builtin_amdgcn_mfma_f32_16x16x32_bf16(aF[1], ones, accl, 0, 0, 0);
    };

    // 2-stage register pipeline (explicit names, static indexing)
    Tile Ta, Tb;
    load_tile(Ta, jt0);
    #pragma unroll 1
    for (int jj = 0; jj < NT; jj += 2) {
        load_tile(Tb, jt0 + jj + 1);           // jj+1 <= 15 always
        process(Ta);
        if (jj + 2 < NT) load_tile(Ta, jt0 + jj + 2);
        process(Tb);
    }

    #pragma unroll
    for (int q = 0; q < 4; ++q)
        #pragma unroll
        for (int r = 0; r < 4; ++r) {
            int io = wv * 16 + lk * 4 + r;
            atomicAdd(&oacc[(size_t)(gi0 + io) * NFLAT + h * 64 + q * 16 + lm], acc[q][r]);
        }
    if (lm == 0) {
        #pragma unroll
        for (int r = 0; r < 4; ++r)
            atomicAdd(&lsumg[h * NN + gi0 + wv * 16 + lk * 4 + r], accl[r]);
    }
}

// ================= normalize + head-sum =================
__global__ __launch_bounds__(256) void k_norm(const float* __restrict__ oacc,
                                              const float* __restrict__ lsumg,
                                              float* __restrict__ out) {
    int t = blockIdx.x * 256 + threadIdx.x;
    int i = t >> 4, fq = (t & 15) * 4;
    float4 s = make_float4(0.f, 0.f, 0.f, 0.f);
    #pragma unroll
    for (int h = 0; h < 8; ++h) {
        float inv = 1.0f / (lsumg[h * NN + i] * (float)NH);
        float4 v = *(const float4*)&oacc[(size_t)i * NFLAT + h * 64 + fq];
        s.x = fmaf(v.x, inv, s.x);
        s.y = fmaf(v.y, inv, s.y);
        s.z = fmaf(v.z, inv, s.z);
        s.w = fmaf(v.w, inv, s.w);
    }
    *(float4*)&out[(size_t)i * FOUT + fq] = s;
}

extern "C" void kernel_launch(void* const* d_in, const int* in_sizes, int n_in,
                              void* d_out, int out_size, void* d_ws, size_t ws_size,
                              hipStream_t stream) {
    const float* x   = (const float*)d_in[0];
    const int*   adj = (const int*)d_in[1];
    const float* W   = (const float*)d_in[2];
    const float* a   = (const float*)d_in[3];
    float* out = (float*)d_out;

    char* ws = (char*)d_ws;
    float* oacc = (float*)ws;           ws += (size_t)NN * NFLAT * 4;   // 8 MiB
    float* f1T = (float*)ws;            ws += (size_t)NH * NN * 4;      // 128 KiB
    float* f2p = (float*)ws;            ws += (size_t)NH * NN * 4;      // 128 KiB
    float* f2n = (float*)ws;            ws += (size_t)NH * NN * 4;      // 128 KiB
    __bf16* whtB = (__bf16*)ws;         ws += (size_t)NFLAT * NN * 2;   // 4 MiB
    unsigned long long* bmT = (unsigned long long*)ws; ws += (size_t)NN * NN / 8; // 2 MiB
    __bf16* wtsw = (__bf16*)ws;         ws += (size_t)FIN * NFLAT * 2;  // 512 KiB
    float* Wa = (float*)ws;             ws += (size_t)FIN * 16 * 4;     // 32 KiB
    float* lsumg = (float*)ws;          ws += (size_t)NH * NN * 4;      // 128 KiB

    k_prep<<<96, 256, 0, stream>>>(W, a, wtsw, Wa);
    k_main<<<1792, 256, 0, stream>>>(x, adj, wtsw, Wa, whtB, f1T, f2p, f2n, bmT, oacc, lsumg);
    k_attn<<<dim3(NN / 64, NH, 4), 256, 0, stream>>>(bmT, whtB, f1T, f2p, f2n, oacc, lsumg);
    k_norm<<<NN * FOUT / 4 / 256, 256, 0, stream>>>(oacc, lsumg, out);
}

// Round 7
// 125.642 us; speedup vs baseline: 1.2758x; 1.2758x over previous
//
#include <hip/hip_runtime.h>

#define LRELU_ALPHA 0.2f

constexpr int NN    = 4096;
constexpr int FIN   = 512;
constexpr int NH    = 8;
constexpr int FOUT  = 64;
constexpr int NFLAT = NH * FOUT; // 512
constexpr float LOG2E = 1.4426950408889634f;

typedef __attribute__((ext_vector_type(8))) __bf16 bf16x8;
typedef __attribute__((ext_vector_type(4))) __bf16 bf16x4;
typedef __attribute__((ext_vector_type(4))) float f32x4;
typedef __attribute__((ext_vector_type(16))) float f32x16;

// ================= k_prep: wtsw + Wa =================
__global__ __launch_bounds__(256) void k_prep(const float* __restrict__ W,
                                              const float* __restrict__ a,
                                              __bf16* __restrict__ wtsw,
                                              float* __restrict__ Wa) {
    __shared__ float tile[64][68];
    const int bid = blockIdx.x;
    const int t = threadIdx.x;
    if (bid < 64) {
        const int kt = bid >> 3;
        const int fb = (bid & 7) * 64;
        {
            const int kk = t >> 2, cq = (t & 3) * 16;
            #pragma unroll
            for (int i = 0; i < 4; ++i)
                *(float4*)&tile[kk][cq + i * 4] =
                    *(const float4*)&W[(size_t)(kt * 64 + kk) * NFLAT + fb + cq + i * 4];
        }
        __syncthreads();
        const int fl = t >> 2;
        #pragma unroll
        for (int c = 0; c < 2; ++c) {
            int gs = (t & 3) * 2 + c;
            int g  = gs ^ (fl & 7);
            bf16x8 o;
            #pragma unroll
            for (int jo = 0; jo < 8; ++jo) o[jo] = (__bf16)tile[g * 8 + jo][fl];
            *(bf16x8*)&wtsw[((size_t)(kt * NFLAT + fb + fl)) * 64 + gs * 8] = o;
        }
    } else {
        const int k = (bid - 64) * 16 + (t >> 4);
        const int o = t & 15;
        const float* wrow = &W[(size_t)k * NFLAT + (o & 7) * 64];
        const float* av   = &a[(o >> 3) * 64];
        float acc = 0.f;
        #pragma unroll 8
        for (int f = 0; f < 64; ++f) acc = fmaf(wrow[f], av[f], acc);
        Wa[k * 16 + o] = acc * LOG2E;
    }
}

// ================= k_main: gemm(->whtsw) + f12(->f1T,f2pn) + bitmask =================
__global__ __launch_bounds__(256) void k_main(const float* __restrict__ x,
                                              const int* __restrict__ adj,
                                              const __bf16* __restrict__ wtsw,
                                              const float* __restrict__ Wa,
                                              __bf16* __restrict__ whtsw,
                                              float* __restrict__ f1T,
                                              float* __restrict__ f2pn,
                                              unsigned long long* __restrict__ bmT,
                                              float* __restrict__ oacc,
                                              float* __restrict__ lsumg) {
    __shared__ alignas(16) __bf16 Bs[2][64 * 64];
    const int bid = blockIdx.x;
    const int t = threadIdx.x;
    if (bid < 512) {
        const int wv = t >> 6, l = t & 63;
        const int jt = bid & 63, h = bid >> 6;
        const int bm = jt * 64, bn = h * 64;
        const int lm = l & 15, lk = l >> 4;
        const int swB = (lm & 7) << 4;

        {
            float4 z = make_float4(0.f, 0.f, 0.f, 0.f);
            float4* od = (float4*)oacc;
            #pragma unroll
            for (int i = 0; i < 4; ++i) od[(size_t)bid * 1024 + t * 4 + i] = z;
            if (bid < 32) ((float4*)lsumg)[bid * 256 + t] = z;
        }

        f32x4 acc[4] = {};
        auto stageB = [&](int kt, int bb) {
            #pragma unroll
            for (int kq = 0; kq < 2; ++kq) {
                int u = t + kq * 256;
                __builtin_amdgcn_global_load_lds(
                    (const __attribute__((address_space(1))) void*)(wtsw + (size_t)(kt * NFLAT + bn) * 64 + u * 8),
                    (__attribute__((address_space(3))) void*)((char*)&Bs[bb][0] + u * 16), 16, 0, 0);
            }
        };

        stageB(0, 0);
        const float* xrow = &x[(size_t)(bm + wv * 16 + lm) * FIN + lk * 8];
        for (int kt = 0; kt < 8; ++kt) {
            bf16x8 aF[2];
            #pragma unroll
            for (int ks = 0; ks < 2; ++ks) {
                float4 u0 = *(const float4*)&xrow[kt * 64 + ks * 32];
                float4 u1 = *(const float4*)&xrow[kt * 64 + ks * 32 + 4];
                bf16x8 af;
                af[0] = (__bf16)u0.x; af[1] = (__bf16)u0.y; af[2] = (__bf16)u0.z; af[3] = (__bf16)u0.w;
                af[4] = (__bf16)u1.x; af[5] = (__bf16)u1.y; af[6] = (__bf16)u1.z; af[7] = (__bf16)u1.w;
                aF[ks] = af;
            }
            __syncthreads();
            if (kt < 7) stageB(kt + 1, (kt + 1) & 1);
            const char* wb = (const char*)&Bs[kt & 1][0];
            #pragma unroll
            for (int q = 0; q < 4; ++q) {
                #pragma unroll
                for (int ks = 0; ks < 2; ++ks) {
                    bf16x8 bF = *(const bf16x8*)(wb + (((q * 16 + lm) * 128 + lk * 16 + ks * 64) ^ swB));
                    acc[q] = __builtin_amdgcn_mfma_f32_16x16x32_bf16(aF[ks], bF, acc[q], 0, 0, 0);
                }
            }
        }
        const int g  = wv * 2 + (lk >> 1);
        const int od = (lk & 1) * 4;
        #pragma unroll
        for (int q = 0; q < 4; ++q) {
            const int f = q * 16 + lm;
            const int pg = g ^ (f & 7);
            bf16x4 o;
            #pragma unroll
            for (int r = 0; r < 4; ++r) o[r] = (__bf16)acc[q][r];
            *(bf16x4*)&whtsw[(size_t)(h * 64 + f) * NN + bm + pg * 8 + od] = o;
        }
    } else if (bid < 768) {
        const int n = (bid - 512) * 16 + (t >> 4);
        const int o = t & 15;
        const float* xrow = &x[(size_t)n * FIN];
        float acc = 0.f;
        for (int k0 = 0; k0 < FIN; k0 += 4) {
            float4 xv = *(const float4*)&xrow[k0];
            acc = fmaf(xv.x, Wa[(k0 + 0) * 16 + o], acc);
            acc = fmaf(xv.y, Wa[(k0 + 1) * 16 + o], acc);
            acc = fmaf(xv.z, Wa[(k0 + 2) * 16 + o], acc);
            acc = fmaf(xv.w, Wa[(k0 + 3) * 16 + o], acc);
        }
        if (o >> 3) {
            float2 v = make_float2(exp2f(acc), exp2f(LRELU_ALPHA * acc));
            *(float2*)&f2pn[2 * ((size_t)(o & 7) * NN + n)] = v;
        } else {
            f1T[(o & 7) * NN + n] = acc;
        }
    } else {
        const size_t base = (size_t)(bid - 768) * 16384;
        for (int it = 0; it < 64; ++it) {
            size_t idx = base + (size_t)it * 256 + t;
            int v = adj[idx];
            unsigned long long b = __ballot(v > 0);
            if ((t & 63) == 0) {
                int i = (int)(idx >> 12);
                int jt = (int)((idx >> 6) & 63);
                bmT[(size_t)jt * NN + i] = b;
            }
        }
    }
}

// ================= k_attn: 32x32x16 MFMA, register-P, LDS-staged B =================
__global__ __launch_bounds__(256, 4) void k_attn(const unsigned long long* __restrict__ bmT,
                                                 const __bf16* __restrict__ whtsw,
                                                 const float* __restrict__ f1T,
                                                 const float* __restrict__ f2pn,
                                                 float* __restrict__ oacc,
                                                 float* __restrict__ lsumg) {
    __shared__ alignas(16) __bf16 Ws[2][64 * 64];

    const int t   = threadIdx.x;
    const int wv  = t >> 6, l = t & 63;
    const int gi0 = blockIdx.x * 128;
    const int h   = blockIdx.y;
    constexpr int NT = 16;
    const int jt0 = blockIdx.z * NT;

    const int lc = l & 31;
    const int hi = l >> 5;
    const int iA = gi0 + wv * 32 + lc;
    const float f1v = f1T[h * NN + iA];
    const float E1p = exp2f(f1v);
    const float E1n = exp2f(LRELU_ALPHA * f1v);

    f32x16 acc0 = {}, acc1 = {};
    float accx = 0.f, accy = 0.f;

    auto stage_W = [&](int jt, int bb) {
        #pragma unroll
        for (int k = 0; k < 2; ++k) {
            int n16 = t + k * 256;
            int f = n16 >> 3, jg = n16 & 7;
            __builtin_amdgcn_global_load_lds(
                (const __attribute__((address_space(1))) void*)(whtsw + (size_t)(h * 64 + f) * NN + jt * 64 + jg * 8),
                (__attribute__((address_space(3))) void*)((char*)&Ws[bb][0] + n16 * 16), 16, 0, 0);
        }
    };

    stage_W(jt0, 0);
    for (int jj = 0; jj < NT; ++jj) {
        const int cur = jj & 1;
        const int jt = jt0 + jj;
        __syncthreads();
        if (jj < NT - 1) stage_W(jt + 1, cur ^ 1);

        const unsigned long long m = bmT[(size_t)jt * NN + iA];
        bf16x8 aF[4];
        #pragma unroll
        for (int js = 0; js < 4; ++js) {
            const float4* pp = (const float4*)&f2pn[2 * ((size_t)h * NN + jt * 64 + js * 16 + hi * 8)];
            unsigned mk = (unsigned)(m >> (js * 16 + hi * 8));
            bf16x8 pk;
            #pragma unroll
            for (int u = 0; u < 4; ++u) {
                float4 vv = pp[u];
                float a0 = fmaxf(E1p * vv.x, E1n * vv.y);
                float a1 = fmaxf(E1p * vv.z, E1n * vv.w);
                unsigned m0 = (unsigned)(((int)(mk << (31 - 2 * u))) >> 31);
                unsigned m1 = (unsigned)(((int)(mk << (30 - 2 * u))) >> 31);
                a0 = __uint_as_float(__float_as_uint(a0) & m0);
                a1 = __uint_as_float(__float_as_uint(a1) & m1);
                __bf16 b0 = (__bf16)a0, b1 = (__bf16)a1;
                accx += (float)b0; accy += (float)b1;
                pk[2 * u] = b0; pk[2 * u + 1] = b1;
            }
            aF[js] = pk;
        }
        const char* wb = (const char*)&Ws[cur][0];
        #pragma unroll
        for (int js = 0; js < 4; ++js) {
            {
                const int fl = lc;
                bf16x8 bF = *(const bf16x8*)(wb + fl * 128 + (((js * 2 + hi) ^ (fl & 7)) << 4));
                acc0 = __builtin_amdgcn_mfma_f32_32x32x16_bf16(aF[js], bF, acc0, 0, 0, 0);
            }
            {
                const int fl = 32 + lc;
                bf16x8 bF = *(const bf16x8*)(wb + fl * 128 + (((js * 2 + hi) ^ (fl & 7)) << 4));
                acc1 = __builtin_amdgcn_mfma_f32_32x32x16_bf16(aF[js], bF, acc1, 0, 0, 0);
            }
        }
    }

    #pragma unroll
    for (int reg = 0; reg < 16; ++reg) {
        const int io = gi0 + wv * 32 + (reg & 3) + 8 * (reg >> 2) + 4 * hi;
        atomicAdd(&oacc[(size_t)io * NFLAT + h * 64 + lc], acc0[reg]);
        atomicAdd(&oacc[(size_t)io * NFLAT + h * 64 + 32 + lc], acc1[reg]);
    }
    atomicAdd(&lsumg[h * NN + iA], accx + accy);
}

// ================= normalize + head-sum =================
__global__ __launch_bounds__(256) void k_norm(const float* __restrict__ oacc,
                                              const float* __restrict__ lsumg,
                                              float* __restrict__ out) {
    int t = blockIdx.x * 256 + threadIdx.x;
    int i = t >> 4, fq = (t & 15) * 4;
    float4 s = make_float4(0.f, 0.f, 0.f, 0.f);
    #pragma unroll
    for (int h = 0; h < 8; ++h) {
        float inv = 1.0f / (lsumg[h * NN + i] * (float)NH);
        float4 v = *(const float4*)&oacc[(size_t)i * NFLAT + h * 64 + fq];
        s.x = fmaf(v.x, inv, s.x);
        s.y = fmaf(v.y, inv, s.y);
        s.z = fmaf(v.z, inv, s.z);
        s.w = fmaf(v.w, inv, s.w);
    }
    *(float4*)&out[(size_t)i * FOUT + fq] = s;
}

extern "C" void kernel_launch(void* const* d_in, const int* in_sizes, int n_in,
                              void* d_out, int out_size, void* d_ws, size_t ws_size,
                              hipStream_t stream) {
    const float* x   = (const float*)d_in[0];
    const int*   adj = (const int*)d_in[1];
    const float* W   = (const float*)d_in[2];
    const float* a   = (const float*)d_in[3];
    float* out = (float*)d_out;

    char* ws = (char*)d_ws;
    float* oacc = (float*)ws;           ws += (size_t)NN * NFLAT * 4;   // 8 MiB
    float* f1T = (float*)ws;            ws += (size_t)NH * NN * 4;      // 128 KiB
    float* f2pn = (float*)ws;           ws += (size_t)NH * NN * 8;      // 256 KiB
    __bf16* whtsw = (__bf16*)ws;        ws += (size_t)NFLAT * NN * 2;   // 4 MiB
    unsigned long long* bmT = (unsigned long long*)ws; ws += (size_t)NN * NN / 8; // 2 MiB
    __bf16* wtsw = (__bf16*)ws;         ws += (size_t)FIN * NFLAT * 2;  // 512 KiB
    float* Wa = (float*)ws;             ws += (size_t)FIN * 16 * 4;     // 32 KiB
    float* lsumg = (float*)ws;          ws += (size_t)NH * NN * 4;      // 128 KiB

    k_prep<<<96, 256, 0, stream>>>(W, a, wtsw, Wa);
    k_main<<<1792, 256, 0, stream>>>(x, adj, wtsw, Wa, whtsw, f1T, f2pn, bmT, oacc, lsumg);
    k_attn<<<dim3(NN / 128, NH, 4), 256, 0, stream>>>(bmT, whtsw, f1T, f2pn, oacc, lsumg);
    k_norm<<<NN * FOUT / 4 / 256, 256, 0, stream>>>(oacc, lsumg, out);
}

// Round 8
// 119.561 us; speedup vs baseline: 1.3407x; 1.0509x over previous
//
#include <hip/hip_runtime.h>

#define LRELU_ALPHA 0.2f

constexpr int NN    = 4096;
constexpr int FIN   = 512;
constexpr int NH    = 8;
constexpr int FOUT  = 64;
constexpr int NFLAT = NH * FOUT; // 512
constexpr float LOG2E = 1.4426950408889634f;

typedef __attribute__((ext_vector_type(8))) __bf16 bf16x8;
typedef __attribute__((ext_vector_type(4))) __bf16 bf16x4;
typedef __attribute__((ext_vector_type(4))) float f32x4;
typedef __attribute__((ext_vector_type(16))) float f32x16;

// ================= k_prep: W -> wtsw (bf16, pre-swizzled) =================
__global__ __launch_bounds__(256) void k_prep(const float* __restrict__ W,
                                              __bf16* __restrict__ wtsw) {
    __shared__ float tile[64][68];
    const int bid = blockIdx.x;
    const int t = threadIdx.x;
    const int kt = bid >> 3;
    const int fb = (bid & 7) * 64;
    {
        const int kk = t >> 2, cq = (t & 3) * 16;
        #pragma unroll
        for (int i = 0; i < 4; ++i)
            *(float4*)&tile[kk][cq + i * 4] =
                *(const float4*)&W[(size_t)(kt * 64 + kk) * NFLAT + fb + cq + i * 4];
    }
    __syncthreads();
    const int fl = t >> 2;
    #pragma unroll
    for (int c = 0; c < 2; ++c) {
        int gs = (t & 3) * 2 + c;
        int g  = gs ^ (fl & 7);
        bf16x8 o;
        #pragma unroll
        for (int jo = 0; jo < 8; ++jo) o[jo] = (__bf16)tile[g * 8 + jo][fl];
        *(bf16x8*)&wtsw[((size_t)(kt * NFLAT + fb + fl)) * 64 + gs * 8] = o;
    }
}

// ================= k_main: gemm(->whtsw, fused f12) + bitmask =================
__global__ __launch_bounds__(256) void k_main(const float* __restrict__ x,
                                              const int* __restrict__ adj,
                                              const float* __restrict__ av,
                                              const __bf16* __restrict__ wtsw,
                                              __bf16* __restrict__ whtsw,
                                              float* __restrict__ f1T,
                                              float* __restrict__ f2pn,
                                              unsigned long long* __restrict__ bmT,
                                              float* __restrict__ oacc,
                                              float* __restrict__ lsumg) {
    __shared__ alignas(16) __bf16 Bs[2][64 * 64];
    const int bid = blockIdx.x;
    const int t = threadIdx.x;
    if (bid < 512) {
        // ---- Wh = bf16(x) @ bf16(W) via 16x16x32 MFMA ----
        const int wv = t >> 6, l = t & 63;
        const int jt = bid & 63, h = bid >> 6;
        const int bm = jt * 64, bn = h * 64;
        const int lm = l & 15, lk = l >> 4;
        const int swB = (lm & 7) << 4;

        // free-rider zero-init of oacc / lsumg
        {
            float4 z = make_float4(0.f, 0.f, 0.f, 0.f);
            float4* od = (float4*)oacc;
            #pragma unroll
            for (int i = 0; i < 4; ++i) od[(size_t)bid * 1024 + t * 4 + i] = z;
            if (bid < 32) ((float4*)lsumg)[bid * 256 + t] = z;
        }

        f32x4 acc[4] = {};
        auto stageB = [&](int kt, int bb) {
            #pragma unroll
            for (int kq = 0; kq < 2; ++kq) {
                int u = t + kq * 256;
                __builtin_amdgcn_global_load_lds(
                    (const __attribute__((address_space(1))) void*)(wtsw + (size_t)(kt * NFLAT + bn) * 64 + u * 8),
                    (__attribute__((address_space(3))) void*)((char*)&Bs[bb][0] + u * 16), 16, 0, 0);
            }
        };

        stageB(0, 0);
        const float* xrow = &x[(size_t)(bm + wv * 16 + lm) * FIN + lk * 8];
        for (int kt = 0; kt < 8; ++kt) {
            bf16x8 aF[2];
            #pragma unroll
            for (int ks = 0; ks < 2; ++ks) {
                float4 u0 = *(const float4*)&xrow[kt * 64 + ks * 32];
                float4 u1 = *(const float4*)&xrow[kt * 64 + ks * 32 + 4];
                bf16x8 af;
                af[0] = (__bf16)u0.x; af[1] = (__bf16)u0.y; af[2] = (__bf16)u0.z; af[3] = (__bf16)u0.w;
                af[4] = (__bf16)u1.x; af[5] = (__bf16)u1.y; af[6] = (__bf16)u1.z; af[7] = (__bf16)u1.w;
                aF[ks] = af;
            }
            __syncthreads();
            if (kt < 7) stageB(kt + 1, (kt + 1) & 1);
            const char* wb = (const char*)&Bs[kt & 1][0];
            #pragma unroll
            for (int q = 0; q < 4; ++q) {
                #pragma unroll
                for (int ks = 0; ks < 2; ++ks) {
                    bf16x8 bF = *(const bf16x8*)(wb + (((q * 16 + lm) * 128 + lk * 16 + ks * 64) ^ swB));
                    acc[q] = __builtin_amdgcn_mfma_f32_16x16x32_bf16(aF[ks], bF, acc[q], 0, 0, 0);
                }
            }
        }
        // ---- epilogue 1: whtsw (transposed + per-64-tile swizzle) ----
        const int g  = wv * 2 + (lk >> 1);
        const int od = (lk & 1) * 4;
        #pragma unroll
        for (int q = 0; q < 4; ++q) {
            const int f = q * 16 + lm;
            const int pg = g ^ (f & 7);
            bf16x4 o;
            #pragma unroll
            for (int r = 0; r < 4; ++r) o[r] = (__bf16)acc[q][r];
            *(bf16x4*)&whtsw[(size_t)(h * 64 + f) * NN + bm + pg * 8 + od] = o;
        }
        // ---- epilogue 2: fused f12 (f1 raw*log2e; f2 -> exp2 pair) ----
        float av1[4], av2[4];
        #pragma unroll
        for (int q = 0; q < 4; ++q) {
            av1[q] = av[q * 16 + lm];
            av2[q] = av[64 + q * 16 + lm];
        }
        float s1[4] = {}, s2[4] = {};
        #pragma unroll
        for (int q = 0; q < 4; ++q)
            #pragma unroll
            for (int r = 0; r < 4; ++r) {
                s1[r] = fmaf(acc[q][r], av1[q], s1[r]);
                s2[r] = fmaf(acc[q][r], av2[q], s2[r]);
            }
        #pragma unroll
        for (int off = 1; off < 16; off <<= 1) {
            #pragma unroll
            for (int r = 0; r < 4; ++r) {
                s1[r] += __shfl_xor(s1[r], off);
                s2[r] += __shfl_xor(s2[r], off);
            }
        }
        if (lm == 0) {
            #pragma unroll
            for (int r = 0; r < 4; ++r) {
                const int io = bm + wv * 16 + lk * 4 + r;
                f1T[h * NN + io] = s1[r] * LOG2E;
                float s2l = s2[r] * LOG2E;
                float2 v = make_float2(exp2f(s2l), exp2f(LRELU_ALPHA * s2l));
                *(float2*)&f2pn[2 * ((size_t)h * NN + io)] = v;
            }
        }
    } else {
        // ---- bitmask pack: adj -> bmT[jt*NN + i] ----
        const size_t base = (size_t)(bid - 512) * 16384;
        for (int it = 0; it < 64; ++it) {
            size_t idx = base + (size_t)it * 256 + t;
            int v = adj[idx];
            unsigned long long b = __ballot(v > 0);
            if ((t & 63) == 0) {
                int i = (int)(idx >> 12);
                int jt = (int)((idx >> 6) & 63);
                bmT[(size_t)jt * NN + i] = b;
            }
        }
    }
}

// ================= k_attn: 32x32x16 MFMA, js-pipelined register-P, LDS-B =================
__global__ __launch_bounds__(256, 4) void k_attn(const unsigned long long* __restrict__ bmT,
                                                 const __bf16* __restrict__ whtsw,
                                                 const float* __restrict__ f1T,
                                                 const float* __restrict__ f2pn,
                                                 float* __restrict__ oacc,
                                                 float* __restrict__ lsumg) {
    __shared__ alignas(16) __bf16 Ws[2][64 * 64];

    const int t   = threadIdx.x;
    const int wv  = t >> 6, l = t & 63;
    const int gi0 = blockIdx.x * 128;
    const int h   = blockIdx.y;
    constexpr int NT = 16;                        // 64 tiles / jsplit 4
    const int jt0 = blockIdx.z * NT;

    const int lc = l & 31, hi = l >> 5;
    const int iA = gi0 + wv * 32 + lc;
    const float f1v = f1T[h * NN + iA];
    const float E1p = exp2f(f1v);
    const float E1n = exp2f(LRELU_ALPHA * f1v);

    f32x16 acc0 = {}, acc1 = {}, accl = {};
    bf16x8 ones;
    #pragma unroll
    for (int e = 0; e < 8; ++e) ones[e] = (__bf16)1.0f;

    const float4* f2base = (const float4*)&f2pn[2 * (size_t)h * NN];  // 2 (p,n) pairs / float4
    const unsigned long long* mbase = bmT + iA;

    auto stage_W = [&](int jt, int bb) {
        #pragma unroll
        for (int k = 0; k < 2; ++k) {
            int n16 = t + k * 256;
            int f = n16 >> 3, jg = n16 & 7;
            __builtin_amdgcn_global_load_lds(
                (const __attribute__((address_space(1))) void*)(whtsw + (size_t)(h * 64 + f) * NN + jt * 64 + jg * 8),
                (__attribute__((address_space(3))) void*)((char*)&Ws[bb][0] + n16 * 16), 16, 0, 0);
        }
    };

    float4 PA[4], PB[4];
    auto ldPF = [&](float4* P, int jt, int js) {
        const float4* pp = f2base + (((size_t)jt * 64 + js * 16 + hi * 8) >> 1);
        P[0] = pp[0]; P[1] = pp[1]; P[2] = pp[2]; P[3] = pp[3];
    };
    auto mathF = [&](const float4* P, unsigned mk) {
        bf16x8 pk;
        #pragma unroll
        for (int u = 0; u < 4; ++u) {
            float a0 = fmaxf(E1p * P[u].x, E1n * P[u].y);
            float a1 = fmaxf(E1p * P[u].z, E1n * P[u].w);
            unsigned m0 = (unsigned)(((int)(mk << (31 - 2 * u))) >> 31);
            unsigned m1 = (unsigned)(((int)(mk << (30 - 2 * u))) >> 31);
            pk[2 * u]     = (__bf16)__uint_as_float(__float_as_uint(a0) & m0);
            pk[2 * u + 1] = (__bf16)__uint_as_float(__float_as_uint(a1) & m1);
        }
        return pk;
    };

    unsigned long long m_cur = mbase[(size_t)jt0 * NN];
    ldPF(PA, jt0, 0);
    stage_W(jt0, 0);

    #pragma unroll 2
    for (int jj = 0; jj < NT; ++jj) {
        const int cur = jj & 1;
        const int jt = jt0 + jj;
        const int jtn = (jj < NT - 1) ? jt + 1 : jt;   // clamped lookahead
        __syncthreads();                               // Ws[cur] ready
        if (jj < NT - 1) stage_W(jt + 1, cur ^ 1);
        unsigned long long m_nxt = mbase[(size_t)jtn * NN];
        const char* wb = (const char*)&Ws[cur][0];
        #pragma unroll
        for (int js = 0; js < 4; ++js) {
            // prefetch next f2pn quad (consumed after ~125 VALU + MFMA)
            if (js < 3) ldPF((js & 1) ? PA : PB, jt, js + 1);
            else if (jj < NT - 1) ldPF(PA, jt + 1, 0);
            bf16x8 aF = mathF((js & 1) ? PB : PA, (unsigned)(m_cur >> (js * 16 + hi * 8)));
            const int sw = ((js * 2 + hi) ^ (lc & 7)) << 4;
            bf16x8 bF0 = *(const bf16x8*)(wb + lc * 128 + sw);
            bf16x8 bF1 = *(const bf16x8*)(wb + (32 + lc) * 128 + sw);
            acc0 = __builtin_amdgcn_mfma_f32_32x32x16_bf16(aF, bF0, acc0, 0, 0, 0);
            acc1 = __builtin_amdgcn_mfma_f32_32x32x16_bf16(aF, bF1, acc1, 0, 0, 0);
            accl = __builtin_amdgcn_mfma_f32_32x32x16_bf16(aF, ones, accl, 0, 0, 0); // rowsum on MFMA pipe
        }
        m_cur = m_nxt;
    }

    // ---- epilogue ----
    #pragma unroll
    for (int reg = 0; reg < 16; ++reg) {
        const int io = gi0 + wv * 32 + (reg & 3) + 8 * (reg >> 2) + 4 * hi;
        atomicAdd(&oacc[(size_t)io * NFLAT + h * 64 + lc], acc0[reg]);
        atomicAdd(&oacc[(size_t)io * NFLAT + h * 64 + 32 + lc], acc1[reg]);
    }
    if (lc == 0) {
        #pragma unroll
        for (int reg = 0; reg < 16; ++reg) {
            const int io = gi0 + wv * 32 + (reg & 3) + 8 * (reg >> 2) + 4 * hi;
            atomicAdd(&lsumg[h * NN + io], accl[reg]);
        }
    }
}

// ================= normalize + head-sum =================
__global__ __launch_bounds__(256) void k_norm(const float* __restrict__ oacc,
                                              const float* __restrict__ lsumg,
                                              float* __restrict__ out) {
    int t = blockIdx.x * 256 + threadIdx.x;
    int i = t >> 4, fq = (t & 15) * 4;
    float4 s = make_float4(0.f, 0.f, 0.f, 0.f);
    #pragma unroll
    for (int h = 0; h < 8; ++h) {
        float inv = 1.0f / (lsumg[h * NN + i] * (float)NH);
        float4 v = *(const float4*)&oacc[(size_t)i * NFLAT + h * 64 + fq];
        s.x = fmaf(v.x, inv, s.x);
        s.y = fmaf(v.y, inv, s.y);
        s.z = fmaf(v.z, inv, s.z);
        s.w = fmaf(v.w, inv, s.w);
    }
    *(float4*)&out[(size_t)i * FOUT + fq] = s;
}

extern "C" void kernel_launch(void* const* d_in, const int* in_sizes, int n_in,
                              void* d_out, int out_size, void* d_ws, size_t ws_size,
                              hipStream_t stream) {
    const float* x   = (const float*)d_in[0];
    const int*   adj = (const int*)d_in[1];
    const float* W   = (const float*)d_in[2];
    const float* a   = (const float*)d_in[3];
    float* out = (float*)d_out;

    char* ws = (char*)d_ws;
    float* oacc = (float*)ws;           ws += (size_t)NN * NFLAT * 4;   // 8 MiB
    float* f1T = (float*)ws;            ws += (size_t)NH * NN * 4;      // 128 KiB
    float* f2pn = (float*)ws;           ws += (size_t)NH * NN * 8;      // 256 KiB
    __bf16* whtsw = (__bf16*)ws;        ws += (size_t)NFLAT * NN * 2;   // 4 MiB
    unsigned long long* bmT = (unsigned long long*)ws; ws += (size_t)NN * NN / 8; // 2 MiB
    __bf16* wtsw = (__bf16*)ws;         ws += (size_t)FIN * NFLAT * 2;  // 512 KiB
    float* lsumg = (float*)ws;          ws += (size_t)NH * NN * 4;      // 128 KiB

    k_prep<<<64, 256, 0, stream>>>(W, wtsw);
    k_main<<<1536, 256, 0, stream>>>(x, adj, a, wtsw, whtsw, f1T, f2pn, bmT, oacc, lsumg);
    k_attn<<<dim3(NN / 128, NH, 4), 256, 0, stream>>>(bmT, whtsw, f1T, f2pn, oacc, lsumg);
    k_norm<<<NN * FOUT / 4 / 256, 256, 0, stream>>>(oacc, lsumg, out);
}